// Round 2
// baseline (1187.338 us; speedup 1.0000x reference)
//
#include <hip/hip_runtime.h>
#include <math.h>

// ---------------------------------------------------------------------------
// B=256 images, each layer tokenizes to N=256 tokens (16x16 after unshuffle).
// Layer1: Cu=12, d=16 (dh=4), local r=16, out 64 ch.
// Layer2: Cu=64, d=32 (dh=8), local r=32, out 128 ch.
// pixel_shuffle(L1) o pixel_unshuffle(L2) == identity => t2 = out1 directly.
// fc1: [256,32768]@[32768,1024] (17.2 GF, the hotspot), fc2: [256,1024]@[1024,10].
// R2: attention rewritten to 1 block/image, per-thread register top-9
//     (replaces 65536-block shuffle-butterfly version: 325 us -> ~15 us pred).
// ---------------------------------------------------------------------------

// ---- workspace layout (float offsets); regions reused, peak ~63 MB ----
static constexpr size_t OQ1 = 0;          // 1048576  [B,256,16]
static constexpr size_t OK1 = 1048576;    // 1048576
static constexpr size_t OV1 = 2097152;    // 1048576
static constexpr size_t OL1 = 3145728;    // 1048576
static constexpr size_t OA1 = 4194304;    // 1048576
static constexpr size_t OT2 = 5242880;    // 4194304  [B,256,64], ends 9437184
static constexpr size_t OQ2 = 0;          // 2097152  (q1/k1 dead after attn1)
static constexpr size_t OK2 = 2097152;    // 2097152  (v1/loc1 dead after out1)
static constexpr size_t OV2 = 9437184;    // 2097152
static constexpr size_t OL2 = 11534336;   // 2097152
static constexpr size_t OA2 = 13631488;   // 2097152, ends 15728640 (peak)
static constexpr size_t OH  = 0;          // 8388608  [B,32768] (q2/k2 dead)
static constexpr size_t OPART = 8388608;  // 16*262144 partials, ends 12582912
static constexpr size_t OHFC  = 12582912; // 262144   [256,1024]

// ---------------- K1: pixel_unshuffle + q/k/v/local projections, layer 1 ----
__global__ __launch_bounds__(256) void k1_qkv1(
    const float* __restrict__ x, const float* __restrict__ w1q,
    const float* __restrict__ w1k, const float* __restrict__ w1v,
    const float* __restrict__ w1c, const float* __restrict__ b1c,
    float* __restrict__ q1, float* __restrict__ k1,
    float* __restrict__ v1, float* __restrict__ loc1)
{
  const int tid = threadIdx.x;
  const int slot = tid >> 6;
  const int lane = tid & 63;
  const int tok = blockIdx.x * 4 + slot;   // b*256+n
  const int b = tok >> 8, n = tok & 255;
  const int i = n >> 4, j = n & 15;
  __shared__ float ts[4][12];
  if (lane < 12) {
    const int c0 = lane >> 2, si = (lane >> 1) & 1, sj = lane & 1;
    ts[slot][lane] = x[((size_t)(b * 3 + c0) * 32 + 2 * i + si) * 32 + 2 * j + sj];
  }
  __syncthreads();
  const int mat = lane >> 4, col = lane & 15;
  const float* W = (mat == 0) ? w1q : (mat == 1) ? w1k : (mat == 2) ? w1v : w1c;
  float acc = 0.f;
#pragma unroll
  for (int c = 0; c < 12; ++c) acc += ts[slot][c] * W[c * 16 + col];
  const size_t o = (size_t)tok * 16 + col;
  if (mat == 0) q1[o] = acc;
  else if (mat == 1) k1[o] = acc;
  else if (mat == 2) v1[o] = acc;
  else loc1[o] = fmaxf(acc + b1c[col], 0.f);
}

// ---------------- attention: 1 block per image, thread t owns token t -------
// K,V staged in LDS once; per-thread running top-9 in registers with
// lax.top_k tie semantics (ascending scan + strict > + evict largest-index
// among equal-min). Then per-head logits/softmax/aggregate, no barriers.
template <int D, int DH, int NHEADS>
__global__ __launch_bounds__(256) void attn_kernel(
    const float* __restrict__ q, const float* __restrict__ k,
    const float* __restrict__ v, float* __restrict__ agg)
{
  const int b = blockIdx.x;
  const int t = threadIdx.x;            // token index n
  __shared__ float ks[256 * D];
  __shared__ float vs[256 * D];
  const size_t base = (size_t)b * 256 * D;
  for (int idx = t * 4; idx < 256 * D; idx += 1024) {
    *(float4*)&ks[idx] = *(const float4*)&k[base + idx];
    *(float4*)&vs[idx] = *(const float4*)&v[base + idx];
  }
  float qr[D];
#pragma unroll
  for (int c = 0; c < D; ++c) qr[c] = q[base + (size_t)t * D + c];
  __syncthreads();

  float topv[9];
  int topi[9];
#pragma unroll
  for (int r = 0; r < 9; ++r) { topv[r] = -__builtin_inff(); topi[r] = 0x7fffffff; }
  int minslot = 0;

#pragma unroll 2
  for (int m = 0; m < 256; ++m) {
    const float4* kr = (const float4*)&ks[m * D];
    float s = 0.f;
#pragma unroll
    for (int c4 = 0; c4 < D / 4; ++c4) {
      const float4 kv = kr[c4];
      s += qr[4 * c4 + 0] * kv.x + qr[4 * c4 + 1] * kv.y +
           qr[4 * c4 + 2] * kv.z + qr[4 * c4 + 3] * kv.w;
    }
    if (s > topv[minslot]) {
      topv[minslot] = s; topi[minslot] = m;
      minslot = 0;
#pragma unroll
      for (int r = 1; r < 9; ++r)
        if (topv[r] < topv[minslot] ||
            (topv[r] == topv[minslot] && topi[r] > topi[minslot]))
          minslot = r;
    }
  }

  // per-head: logits over the 9 selected, softmax, aggregate V
  const float scale = (DH == 4) ? 0.5f : 0.35355339059327373f;
  float outr[D];
#pragma unroll
  for (int hh = 0; hh < NHEADS; ++hh) {
    float lg[9];
#pragma unroll
    for (int kk = 0; kk < 9; ++kk) {
      const float* krow = &ks[topi[kk] * D + hh * DH];
      float s = 0.f;
#pragma unroll
      for (int c = 0; c < DH; ++c) s += qr[hh * DH + c] * krow[c];
      lg[kk] = s * scale;
    }
    float mx = lg[0];
#pragma unroll
    for (int kk = 1; kk < 9; ++kk) mx = fmaxf(mx, lg[kk]);
    float e[9]; float sum = 0.f;
#pragma unroll
    for (int kk = 0; kk < 9; ++kk) { e[kk] = __expf(lg[kk] - mx); sum += e[kk]; }
    const float inv = 1.f / sum;
#pragma unroll
    for (int c = 0; c < DH; ++c) outr[hh * DH + c] = 0.f;
#pragma unroll
    for (int kk = 0; kk < 9; ++kk) {
      const float w = e[kk] * inv;
      const float* vrow = &vs[topi[kk] * D + hh * DH];
#pragma unroll
      for (int c = 0; c < DH; ++c) outr[hh * DH + c] += w * vrow[c];
    }
  }
  float* o = agg + base + (size_t)t * D;
#pragma unroll
  for (int c = 0; c < D; ++c) o[c] = outr[c];
}

// ---------------- K3: concat(local,agg) @ W1o + b1o -> t2 [B,256,64] --------
__global__ __launch_bounds__(256) void k3_out1(
    const float* __restrict__ loc1, const float* __restrict__ agg1,
    const float* __restrict__ w1o, const float* __restrict__ b1o,
    float* __restrict__ t2)
{
  const int tid = threadIdx.x;
  const int slot = tid >> 6, col = tid & 63;
  const int tok = blockIdx.x * 4 + slot;
  __shared__ float cat[4][32];
  if (col < 16) {
    cat[slot][col] = loc1[(size_t)tok * 16 + col];
    cat[slot][col + 16] = agg1[(size_t)tok * 16 + col];
  }
  __syncthreads();
  float acc = b1o[col];
#pragma unroll
  for (int c = 0; c < 32; ++c) acc += cat[slot][c] * w1o[c * 64 + col];
  t2[(size_t)tok * 64 + col] = acc;
}

// ---------------- K4: q/k/v/local projections, layer 2 ----------------------
__global__ __launch_bounds__(256) void k4_qkv2(
    const float* __restrict__ t2, const float* __restrict__ w2q,
    const float* __restrict__ w2k, const float* __restrict__ w2v,
    const float* __restrict__ w2c, const float* __restrict__ b2c,
    float* __restrict__ q2, float* __restrict__ k2,
    float* __restrict__ v2, float* __restrict__ loc2)
{
  const int tid = threadIdx.x;
  const int slot = tid >> 7, r = tid & 127;
  const int tok = blockIdx.x * 2 + slot;
  __shared__ float ts[2][64];
  if (r < 64) ts[slot][r] = t2[(size_t)tok * 64 + r];
  __syncthreads();
  const int mat = r >> 5, col = r & 31;
  const float* W = (mat == 0) ? w2q : (mat == 1) ? w2k : (mat == 2) ? w2v : w2c;
  float acc = 0.f;
#pragma unroll
  for (int c = 0; c < 64; ++c) acc += ts[slot][c] * W[c * 32 + col];
  const size_t o = (size_t)tok * 32 + col;
  if (mat == 0) q2[o] = acc;
  else if (mat == 1) k2[o] = acc;
  else if (mat == 2) v2[o] = acc;
  else loc2[o] = fmaxf(acc + b2c[col], 0.f);
}

// ---------------- K6: out-proj layer2 + pixel_shuffle scatter into h --------
__global__ __launch_bounds__(256) void k6_out2(
    const float* __restrict__ loc2, const float* __restrict__ agg2,
    const float* __restrict__ w2o, const float* __restrict__ b2o,
    float* __restrict__ h)
{
  const int tid = threadIdx.x;
  const int slot = tid >> 7, ch = tid & 127;
  const int tok = blockIdx.x * 2 + slot;
  const int b = tok >> 8, n = tok & 255;
  __shared__ float cat[2][64];
  if (ch < 32) {
    cat[slot][ch] = loc2[(size_t)tok * 32 + ch];
    cat[slot][ch + 32] = agg2[(size_t)tok * 32 + ch];
  }
  __syncthreads();
  float acc = b2o[ch];
#pragma unroll
  for (int c = 0; c < 64; ++c) acc += cat[slot][c] * w2o[c * 128 + ch];
  const int i = n >> 4, j = n & 15;
  const int cc = ch >> 2, si = (ch >> 1) & 1, sj = ch & 1;
  h[(size_t)b * 32768 + cc * 1024 + (2 * i + si) * 32 + (2 * j + sj)] = acc;
}

// ---------------- K7: fc1 GEMM fp32, 64x64 tile, 4x4 microtile, split-K=16 --
__global__ __launch_bounds__(256) void k7_fc1_gemm(
    const float* __restrict__ A,   // h [256, 32768]
    const float* __restrict__ Bw,  // fc1_w [32768, 1024]
    float* __restrict__ part)      // [16][256][1024]
{
  const int bid = blockIdx.x;
  const int bm = bid & 3;          // 4 M-tiles
  const int bn = (bid >> 2) & 15;  // 16 N-tiles
  const int bk = bid >> 6;         // 16 K-chunks of 2048
  const int m0 = bm * 64, n0 = bn * 64, k0 = bk * 2048;
  __shared__ float As[32][68];     // As[kk][r], pad 68 keeps float4 aligned
  __shared__ float Bs[32][64];
  const int tid = threadIdx.x;
  const int r0 = (tid >> 4) * 4;
  const int c0 = (tid & 15) * 4;
  const int ar = tid >> 3;         // 0..31
  const int ak4 = (tid & 7) * 4;   // 0..28
  const int bro = tid >> 4;        // 0..15
  const int bc4 = (tid & 15) * 4;  // 0..60
  float acc[4][4];
#pragma unroll
  for (int i = 0; i < 4; ++i)
#pragma unroll
    for (int jj = 0; jj < 4; ++jj) acc[i][jj] = 0.f;

  for (int kb = k0; kb < k0 + 2048; kb += 32) {
    const float4 a1 = *(const float4*)(A + (size_t)(m0 + ar) * 32768 + kb + ak4);
    const float4 a2 = *(const float4*)(A + (size_t)(m0 + ar + 32) * 32768 + kb + ak4);
    const float4 b1 = *(const float4*)(Bw + (size_t)(kb + bro) * 1024 + n0 + bc4);
    const float4 b2 = *(const float4*)(Bw + (size_t)(kb + bro + 16) * 1024 + n0 + bc4);
    __syncthreads();  // previous iteration's LDS reads done
    As[ak4 + 0][ar] = a1.x; As[ak4 + 1][ar] = a1.y;
    As[ak4 + 2][ar] = a1.z; As[ak4 + 3][ar] = a1.w;
    As[ak4 + 0][ar + 32] = a2.x; As[ak4 + 1][ar + 32] = a2.y;
    As[ak4 + 2][ar + 32] = a2.z; As[ak4 + 3][ar + 32] = a2.w;
    *(float4*)&Bs[bro][bc4] = b1;
    *(float4*)&Bs[bro + 16][bc4] = b2;
    __syncthreads();
#pragma unroll
    for (int kk = 0; kk < 32; ++kk) {
      const float4 av = *(const float4*)&As[kk][r0];
      const float4 bv = *(const float4*)&Bs[kk][c0];
      acc[0][0] += av.x * bv.x; acc[0][1] += av.x * bv.y; acc[0][2] += av.x * bv.z; acc[0][3] += av.x * bv.w;
      acc[1][0] += av.y * bv.x; acc[1][1] += av.y * bv.y; acc[1][2] += av.y * bv.z; acc[1][3] += av.y * bv.w;
      acc[2][0] += av.z * bv.x; acc[2][1] += av.z * bv.y; acc[2][2] += av.z * bv.z; acc[2][3] += av.z * bv.w;
      acc[3][0] += av.w * bv.x; acc[3][1] += av.w * bv.y; acc[3][2] += av.w * bv.z; acc[3][3] += av.w * bv.w;
    }
  }
  float* P = part + (size_t)bk * 262144;
#pragma unroll
  for (int i = 0; i < 4; ++i) {
    const float4 st = make_float4(acc[i][0], acc[i][1], acc[i][2], acc[i][3]);
    *(float4*)(P + (size_t)(m0 + r0 + i) * 1024 + n0 + c0) = st;
  }
}

// ---------------- K7c: reduce split-K partials ------------------------------
__global__ __launch_bounds__(256) void k7c_reduce(
    const float* __restrict__ part, float* __restrict__ hfc)
{
  const int idx = blockIdx.x * 256 + threadIdx.x;  // 262144 total
  float s = 0.f;
#pragma unroll
  for (int p = 0; p < 16; ++p) s += part[(size_t)p * 262144 + idx];
  hfc[idx] = s;
}

// ---------------- K8: bias+relu fused into fc2 ------------------------------
__global__ __launch_bounds__(256) void k8_fc2(
    const float* __restrict__ hfc, const float* __restrict__ fc1b,
    const float* __restrict__ w2, const float* __restrict__ b2,
    float* __restrict__ out)
{
  const int b = blockIdx.x, t = threadIdx.x;
  float acc[10];
#pragma unroll
  for (int o = 0; o < 10; ++o) acc[o] = 0.f;
  for (int jj = t; jj < 1024; jj += 256) {
    const float a = fmaxf(hfc[(size_t)b * 1024 + jj] + fc1b[jj], 0.f);
    const float* wr = w2 + (size_t)jj * 10;
#pragma unroll
    for (int o = 0; o < 10; ++o) acc[o] += a * wr[o];
  }
  __shared__ float red[256][10];
#pragma unroll
  for (int o = 0; o < 10; ++o) red[t][o] = acc[o];
  __syncthreads();
  for (int s = 128; s > 0; s >>= 1) {
    if (t < s) {
#pragma unroll
      for (int o = 0; o < 10; ++o) red[t][o] += red[t + s][o];
    }
    __syncthreads();
  }
  if (t < 10) out[b * 10 + t] = red[0][t] + b2[t];
}

// ---------------------------------------------------------------------------
extern "C" void kernel_launch(void* const* d_in, const int* in_sizes, int n_in,
                              void* d_out, int out_size, void* d_ws, size_t ws_size,
                              hipStream_t stream)
{
  const float* x    = (const float*)d_in[0];
  const float* w1c  = (const float*)d_in[1];
  const float* b1c  = (const float*)d_in[2];
  const float* w1q  = (const float*)d_in[3];
  const float* w1k  = (const float*)d_in[4];
  const float* w1v  = (const float*)d_in[5];
  const float* w1o  = (const float*)d_in[6];
  const float* b1o  = (const float*)d_in[7];
  const float* w2c  = (const float*)d_in[8];
  const float* b2c  = (const float*)d_in[9];
  const float* w2q  = (const float*)d_in[10];
  const float* w2k  = (const float*)d_in[11];
  const float* w2v  = (const float*)d_in[12];
  const float* w2o  = (const float*)d_in[13];
  const float* b2o  = (const float*)d_in[14];
  const float* fc1w = (const float*)d_in[15];
  const float* fc1b = (const float*)d_in[16];
  const float* fc2w = (const float*)d_in[17];
  const float* fc2b = (const float*)d_in[18];
  float* out = (float*)d_out;
  float* ws = (float*)d_ws;

  float* q1   = ws + OQ1;
  float* k1   = ws + OK1;
  float* v1   = ws + OV1;
  float* loc1 = ws + OL1;
  float* agg1 = ws + OA1;
  float* t2   = ws + OT2;
  float* q2   = ws + OQ2;
  float* k2   = ws + OK2;
  float* v2   = ws + OV2;
  float* loc2 = ws + OL2;
  float* agg2 = ws + OA2;
  float* h    = ws + OH;
  float* prt  = ws + OPART;
  float* hfc  = ws + OHFC;

  k1_qkv1<<<16384, 256, 0, stream>>>(x, w1q, w1k, w1v, w1c, b1c, q1, k1, v1, loc1);
  attn_kernel<16, 4, 4><<<256, 256, 0, stream>>>(q1, k1, v1, agg1);
  k3_out1<<<16384, 256, 0, stream>>>(loc1, agg1, w1o, b1o, t2);
  k4_qkv2<<<32768, 256, 0, stream>>>(t2, w2q, w2k, w2v, w2c, b2c, q2, k2, v2, loc2);
  attn_kernel<32, 8, 4><<<256, 256, 0, stream>>>(q2, k2, v2, agg2);
  k6_out2<<<32768, 256, 0, stream>>>(loc2, agg2, w2o, b2o, h);
  k7_fc1_gemm<<<1024, 256, 0, stream>>>(h, fc1w, prt);
  k7c_reduce<<<1024, 256, 0, stream>>>(prt, hfc);
  k8_fc2<<<256, 256, 0, stream>>>(hfc, fc1b, fc2w, fc2b, out);
}

// Round 3
// 691.939 us; speedup vs baseline: 1.7160x; 1.7160x over previous
//
#include <hip/hip_runtime.h>
#include <math.h>

// ---------------------------------------------------------------------------
// B=256 images, layers tokenize to N=256 tokens (16x16 after unshuffle).
// L1: Cu=12, d=16 (dh=4), local r=16 -> 64ch. L2: Cu=64, d=32 (dh=8) -> 128ch.
// pixel_shuffle(L1) o pixel_unshuffle(L2) == identity => t2 = out1 directly.
// R3: attn = branchless static-index top-9 (no movrel/scratch, no divergence),
//     phase-2/3 gathers from global (kills 64-way LDS bank conflicts);
//     fc1 = bf16 MFMA 16x16x32, BM=256 BN=64 splitK=16, W cvt fused in staging.
// ---------------------------------------------------------------------------

typedef float floatx4 __attribute__((ext_vector_type(4)));
typedef __bf16 bf16x8 __attribute__((ext_vector_type(8)));

// ---- workspace layout (float offsets) ----
static constexpr size_t OQ1 = 0;          // 1048576  [B,256,16]
static constexpr size_t OK1 = 1048576;    // 1048576
static constexpr size_t OV1 = 2097152;    // 1048576
static constexpr size_t OL1 = 3145728;    // 1048576
static constexpr size_t OA1 = 4194304;    // 1048576
static constexpr size_t OT2 = 5242880;    // 4194304  [B,256,64], ends 9437184
static constexpr size_t OQ2 = 0;          // 2097152  (q1/k1 dead after attn1)
static constexpr size_t OK2 = 2097152;    // 2097152
static constexpr size_t OV2 = 9437184;    // 2097152
static constexpr size_t OL2 = 11534336;   // 2097152
static constexpr size_t OA2 = 13631488;   // 2097152, ends 15728640 (peak 63MB)
static constexpr size_t OH  = 0;          // h as bf16 [256,32768] = 4194304 floats
static constexpr size_t OPART = 4194304;  // 16*262144 fp32, ends 8388608
static constexpr size_t OHFC  = 8388608;  // 262144   [256,1024]

// ---------------- K1: pixel_unshuffle + q/k/v/local projections, layer 1 ----
__global__ __launch_bounds__(256) void k1_qkv1(
    const float* __restrict__ x, const float* __restrict__ w1q,
    const float* __restrict__ w1k, const float* __restrict__ w1v,
    const float* __restrict__ w1c, const float* __restrict__ b1c,
    float* __restrict__ q1, float* __restrict__ k1,
    float* __restrict__ v1, float* __restrict__ loc1)
{
  const int tid = threadIdx.x;
  const int slot = tid >> 6;
  const int lane = tid & 63;
  const int tok = blockIdx.x * 4 + slot;   // b*256+n
  const int b = tok >> 8, n = tok & 255;
  const int i = n >> 4, j = n & 15;
  __shared__ float ts[4][12];
  if (lane < 12) {
    const int c0 = lane >> 2, si = (lane >> 1) & 1, sj = lane & 1;
    ts[slot][lane] = x[((size_t)(b * 3 + c0) * 32 + 2 * i + si) * 32 + 2 * j + sj];
  }
  __syncthreads();
  const int mat = lane >> 4, col = lane & 15;
  const float* W = (mat == 0) ? w1q : (mat == 1) ? w1k : (mat == 2) ? w1v : w1c;
  float acc = 0.f;
#pragma unroll
  for (int c = 0; c < 12; ++c) acc += ts[slot][c] * W[c * 16 + col];
  const size_t o = (size_t)tok * 16 + col;
  if (mat == 0) q1[o] = acc;
  else if (mat == 1) k1[o] = acc;
  else if (mat == 2) v1[o] = acc;
  else loc1[o] = fmaxf(acc + b1c[col], 0.f);
}

// ---------------- attention: 1 block/image, thread t owns token t -----------
// K staged in LDS (scan reuses it 256x, broadcast reads = conflict-free).
// Top-9 via branchless sorted-insert shift network (static indices only).
// Phase 2/3 (logits/softmax/aggregate) gather K,V rows from global (L2).
template <int D, int DH, int NHEADS>
__global__ __launch_bounds__(256) void attn_kernel(
    const float* __restrict__ q, const float* __restrict__ k,
    const float* __restrict__ v, float* __restrict__ agg)
{
  const int b = blockIdx.x;
  const int t = threadIdx.x;            // token index n
  __shared__ float ks[256 * D];
  const size_t base = (size_t)b * (256 * D);
  for (int idx = t * 4; idx < 256 * D; idx += 1024)
    *(float4*)&ks[idx] = *(const float4*)&k[base + idx];
  float qr[D];
  {
    const float4* qrow = (const float4*)&q[base + (size_t)t * D];
#pragma unroll
    for (int c4 = 0; c4 < D / 4; ++c4) {
      const float4 qv = qrow[c4];
      qr[4 * c4 + 0] = qv.x; qr[4 * c4 + 1] = qv.y;
      qr[4 * c4 + 2] = qv.z; qr[4 * c4 + 3] = qv.w;
    }
  }
  __syncthreads();

  float topv[9];
  int topi[9];
#pragma unroll
  for (int r = 0; r < 9; ++r) { topv[r] = -__builtin_inff(); topi[r] = 0; }

#pragma unroll 2
  for (int m = 0; m < 256; ++m) {
    const float4* kr = (const float4*)&ks[m * D];
    float p0 = 0.f, p1 = 0.f, p2 = 0.f, p3 = 0.f;
#pragma unroll
    for (int c4 = 0; c4 < D / 4; c4 += 4) {
      float4 kv;
      kv = kr[c4 + 0];
      p0 += qr[4 * c4 + 0] * kv.x + qr[4 * c4 + 1] * kv.y +
            qr[4 * c4 + 2] * kv.z + qr[4 * c4 + 3] * kv.w;
      if (D / 4 > 1) {
        kv = kr[c4 + 1];
        p1 += qr[4 * c4 + 4] * kv.x + qr[4 * c4 + 5] * kv.y +
              qr[4 * c4 + 6] * kv.z + qr[4 * c4 + 7] * kv.w;
      }
      if (D / 4 > 2) {
        kv = kr[c4 + 2];
        p2 += qr[4 * c4 + 8] * kv.x + qr[4 * c4 + 9] * kv.y +
              qr[4 * c4 + 10] * kv.z + qr[4 * c4 + 11] * kv.w;
        kv = kr[c4 + 3];
        p3 += qr[4 * c4 + 12] * kv.x + qr[4 * c4 + 13] * kv.y +
              qr[4 * c4 + 14] * kv.z + qr[4 * c4 + 15] * kv.w;
      }
    }
    const float s = (p0 + p1) + (p2 + p3);
    // branchless sorted insert (descending). Strict > + ascending-m stream
    // == lax.top_k stable tie semantics (lowest index first).
    bool ci = s > topv[8];
#pragma unroll
    for (int i = 8; i >= 1; --i) {
      const bool cim1 = s > topv[i - 1];
      topv[i] = ci ? (cim1 ? topv[i - 1] : s) : topv[i];
      topi[i] = ci ? (cim1 ? topi[i - 1] : m) : topi[i];
      ci = cim1;
    }
    topv[0] = ci ? s : topv[0];
    topi[0] = ci ? m : topi[0];
  }

  // phase 2: per-head logits from global K rows (L2-resident)
  const float scale = (DH == 4) ? 0.5f : 0.35355339059327373f;
  float lg[NHEADS * 9];
#pragma unroll
  for (int kk = 0; kk < 9; ++kk) {
    const float4* kr = (const float4*)&k[base + (size_t)topi[kk] * D];
    float kv[D];
#pragma unroll
    for (int c4 = 0; c4 < D / 4; ++c4) {
      const float4 x4 = kr[c4];
      kv[4 * c4 + 0] = x4.x; kv[4 * c4 + 1] = x4.y;
      kv[4 * c4 + 2] = x4.z; kv[4 * c4 + 3] = x4.w;
    }
#pragma unroll
    for (int hh = 0; hh < NHEADS; ++hh) {
      float s = 0.f;
#pragma unroll
      for (int c = 0; c < DH; ++c) s += qr[hh * DH + c] * kv[hh * DH + c];
      lg[hh * 9 + kk] = s * scale;
    }
  }
  // softmax per head (weights overwrite lg)
#pragma unroll
  for (int hh = 0; hh < NHEADS; ++hh) {
    float mx = lg[hh * 9];
#pragma unroll
    for (int kk = 1; kk < 9; ++kk) mx = fmaxf(mx, lg[hh * 9 + kk]);
    float sum = 0.f;
#pragma unroll
    for (int kk = 0; kk < 9; ++kk) {
      const float e = __expf(lg[hh * 9 + kk] - mx);
      lg[hh * 9 + kk] = e; sum += e;
    }
    const float inv = 1.f / sum;
#pragma unroll
    for (int kk = 0; kk < 9; ++kk) lg[hh * 9 + kk] *= inv;
  }
  // phase 3: aggregate V rows from global
  float outr[D];
#pragma unroll
  for (int c = 0; c < D; ++c) outr[c] = 0.f;
#pragma unroll
  for (int kk = 0; kk < 9; ++kk) {
    const float4* vr = (const float4*)&v[base + (size_t)topi[kk] * D];
    float vv[D];
#pragma unroll
    for (int c4 = 0; c4 < D / 4; ++c4) {
      const float4 x4 = vr[c4];
      vv[4 * c4 + 0] = x4.x; vv[4 * c4 + 1] = x4.y;
      vv[4 * c4 + 2] = x4.z; vv[4 * c4 + 3] = x4.w;
    }
#pragma unroll
    for (int hh = 0; hh < NHEADS; ++hh) {
      const float w = lg[hh * 9 + kk];
#pragma unroll
      for (int c = 0; c < DH; ++c) outr[hh * DH + c] += w * vv[hh * DH + c];
    }
  }
  float4* o = (float4*)&agg[base + (size_t)t * D];
#pragma unroll
  for (int c4 = 0; c4 < D / 4; ++c4)
    o[c4] = make_float4(outr[4 * c4], outr[4 * c4 + 1], outr[4 * c4 + 2], outr[4 * c4 + 3]);
}

// ---------------- K3: concat(local,agg) @ W1o + b1o -> t2 [B,256,64] --------
__global__ __launch_bounds__(256) void k3_out1(
    const float* __restrict__ loc1, const float* __restrict__ agg1,
    const float* __restrict__ w1o, const float* __restrict__ b1o,
    float* __restrict__ t2)
{
  const int tid = threadIdx.x;
  const int slot = tid >> 6, col = tid & 63;
  const int tok = blockIdx.x * 4 + slot;
  __shared__ float cat[4][32];
  if (col < 16) {
    cat[slot][col] = loc1[(size_t)tok * 16 + col];
    cat[slot][col + 16] = agg1[(size_t)tok * 16 + col];
  }
  __syncthreads();
  float acc = b1o[col];
#pragma unroll
  for (int c = 0; c < 32; ++c) acc += cat[slot][c] * w1o[c * 64 + col];
  t2[(size_t)tok * 64 + col] = acc;
}

// ---------------- K4: q/k/v/local projections, layer 2 ----------------------
__global__ __launch_bounds__(256) void k4_qkv2(
    const float* __restrict__ t2, const float* __restrict__ w2q,
    const float* __restrict__ w2k, const float* __restrict__ w2v,
    const float* __restrict__ w2c, const float* __restrict__ b2c,
    float* __restrict__ q2, float* __restrict__ k2,
    float* __restrict__ v2, float* __restrict__ loc2)
{
  const int tid = threadIdx.x;
  const int slot = tid >> 7, r = tid & 127;
  const int tok = blockIdx.x * 2 + slot;
  __shared__ float ts[2][64];
  if (r < 64) ts[slot][r] = t2[(size_t)tok * 64 + r];
  __syncthreads();
  const int mat = r >> 5, col = r & 31;
  const float* W = (mat == 0) ? w2q : (mat == 1) ? w2k : (mat == 2) ? w2v : w2c;
  float acc = 0.f;
#pragma unroll
  for (int c = 0; c < 64; ++c) acc += ts[slot][c] * W[c * 32 + col];
  const size_t o = (size_t)tok * 32 + col;
  if (mat == 0) q2[o] = acc;
  else if (mat == 1) k2[o] = acc;
  else if (mat == 2) v2[o] = acc;
  else loc2[o] = fmaxf(acc + b2c[col], 0.f);
}

// ---------------- K6: out-proj layer2 + pixel_shuffle scatter -> h (bf16) ---
__global__ __launch_bounds__(256) void k6_out2(
    const float* __restrict__ loc2, const float* __restrict__ agg2,
    const float* __restrict__ w2o, const float* __restrict__ b2o,
    __bf16* __restrict__ h)
{
  const int tid = threadIdx.x;
  const int slot = tid >> 7, ch = tid & 127;
  const int tok = blockIdx.x * 2 + slot;
  const int b = tok >> 8, n = tok & 255;
  __shared__ float cat[2][64];
  if (ch < 32) {
    cat[slot][ch] = loc2[(size_t)tok * 32 + ch];
    cat[slot][ch + 32] = agg2[(size_t)tok * 32 + ch];
  }
  __syncthreads();
  float acc = b2o[ch];
#pragma unroll
  for (int c = 0; c < 64; ++c) acc += cat[slot][c] * w2o[c * 128 + ch];
  const int i = n >> 4, j = n & 15;
  const int cc = ch >> 2, si = (ch >> 1) & 1, sj = ch & 1;
  h[(size_t)b * 32768 + cc * 1024 + (2 * i + si) * 32 + (2 * j + sj)] = (__bf16)acc;
}

// ---------------- K7: fc1 GEMM bf16 MFMA. BM=256(all M) BN=64, splitK=16 ----
// grid 256 blocks (bn = blk&15, bk = blk>>4), 256 thr = 4 waves.
// Wave w owns rows w*64..w*64+63: 4x4 grid of 16x16x32 mfma over 64 cols.
// A (h) already bf16; B (fc1_w) converted fp32->bf16 during staging, so W is
// fetched from HBM exactly once across the grid (134 MB).
__global__ __launch_bounds__(256) void k7_fc1_gemm(
    const __bf16* __restrict__ A,  // h bf16 [256, 32768]
    const float* __restrict__ Bw,  // fc1_w fp32 [32768, 1024]
    float* __restrict__ part)      // [16][256][1024]
{
  constexpr int LDA = 40;  // bf16 elems per As row (32 + 8 pad)
  __shared__ __bf16 As[256 * LDA];  // [m][k] 20 KB
  __shared__ __bf16 Bs[64 * LDA];   // [n][k] 5 KB (transposed for B-frag reads)
  const int bn = blockIdx.x & 15, bk = blockIdx.x >> 4;
  const int n0 = bn * 64;
  const int k0 = bk * 2048;
  const int tid = threadIdx.x;
  const int w = tid >> 6, lane = tid & 63;
  const int qd = lane >> 4, mcol = lane & 15;
  // staging indices
  const int brow = tid >> 3;        // B: k index 0..31
  const int bn8 = (tid & 7) * 8;    // B: n chunk
  floatx4 acc[4][4];
#pragma unroll
  for (int mi = 0; mi < 4; ++mi)
#pragma unroll
    for (int ni = 0; ni < 4; ++ni) acc[mi][ni] = (floatx4)0.f;

  for (int it = 0; it < 64; ++it) {
    const int kk0 = k0 + it * 32;
    // global loads into regs
    uint4 av[4];
    const uint4* arow = (const uint4*)(A + (size_t)tid * 32768 + kk0);
#pragma unroll
    for (int jj = 0; jj < 4; ++jj) av[jj] = arow[jj];
    float4 bv0 = *(const float4*)(Bw + (size_t)(kk0 + brow) * 1024 + n0 + bn8);
    float4 bv1 = *(const float4*)(Bw + (size_t)(kk0 + brow) * 1024 + n0 + bn8 + 4);
    __syncthreads();  // previous iteration's LDS reads complete
#pragma unroll
    for (int jj = 0; jj < 4; ++jj)
      *(uint4*)&As[tid * LDA + jj * 8] = av[jj];
    Bs[(bn8 + 0) * LDA + brow] = (__bf16)bv0.x;
    Bs[(bn8 + 1) * LDA + brow] = (__bf16)bv0.y;
    Bs[(bn8 + 2) * LDA + brow] = (__bf16)bv0.z;
    Bs[(bn8 + 3) * LDA + brow] = (__bf16)bv0.w;
    Bs[(bn8 + 4) * LDA + brow] = (__bf16)bv1.x;
    Bs[(bn8 + 5) * LDA + brow] = (__bf16)bv1.y;
    Bs[(bn8 + 6) * LDA + brow] = (__bf16)bv1.z;
    Bs[(bn8 + 7) * LDA + brow] = (__bf16)bv1.w;
    __syncthreads();
    bf16x8 af[4], bf[4];
#pragma unroll
    for (int mi = 0; mi < 4; ++mi)
      af[mi] = *(const bf16x8*)&As[(w * 64 + mi * 16 + mcol) * LDA + qd * 8];
#pragma unroll
    for (int ni = 0; ni < 4; ++ni)
      bf[ni] = *(const bf16x8*)&Bs[(ni * 16 + mcol) * LDA + qd * 8];
#pragma unroll
    for (int mi = 0; mi < 4; ++mi)
#pragma unroll
      for (int ni = 0; ni < 4; ++ni)
        acc[mi][ni] = __builtin_amdgcn_mfma_f32_16x16x32_bf16(af[mi], bf[ni], acc[mi][ni], 0, 0, 0);
  }
  // epilogue: C/D layout col=lane&15, row=(lane>>4)*4+reg
  float* P = part + (size_t)bk * 262144;
#pragma unroll
  for (int mi = 0; mi < 4; ++mi)
#pragma unroll
    for (int ni = 0; ni < 4; ++ni) {
      const int col = n0 + ni * 16 + mcol;
#pragma unroll
      for (int r = 0; r < 4; ++r) {
        const int row = w * 64 + mi * 16 + qd * 4 + r;
        P[(size_t)row * 1024 + col] = acc[mi][ni][r];
      }
    }
}

// ---------------- K7c: reduce split-K partials ------------------------------
__global__ __launch_bounds__(256) void k7c_reduce(
    const float* __restrict__ part, float* __restrict__ hfc)
{
  const int idx = blockIdx.x * 256 + threadIdx.x;  // 262144 total
  float s = 0.f;
#pragma unroll
  for (int p = 0; p < 16; ++p) s += part[(size_t)p * 262144 + idx];
  hfc[idx] = s;
}

// ---------------- K8: bias+relu fused into fc2 ------------------------------
__global__ __launch_bounds__(256) void k8_fc2(
    const float* __restrict__ hfc, const float* __restrict__ fc1b,
    const float* __restrict__ w2, const float* __restrict__ b2,
    float* __restrict__ out)
{
  const int b = blockIdx.x, t = threadIdx.x;
  float acc[10];
#pragma unroll
  for (int o = 0; o < 10; ++o) acc[o] = 0.f;
  for (int jj = t; jj < 1024; jj += 256) {
    const float a = fmaxf(hfc[(size_t)b * 1024 + jj] + fc1b[jj], 0.f);
    const float* wr = w2 + (size_t)jj * 10;
#pragma unroll
    for (int o = 0; o < 10; ++o) acc[o] += a * wr[o];
  }
  __shared__ float red[256][10];
#pragma unroll
  for (int o = 0; o < 10; ++o) red[t][o] = acc[o];
  __syncthreads();
  for (int s = 128; s > 0; s >>= 1) {
    if (t < s) {
#pragma unroll
      for (int o = 0; o < 10; ++o) red[t][o] += red[t + s][o];
    }
    __syncthreads();
  }
  if (t < 10) out[b * 10 + t] = red[0][t] + b2[t];
}

// ---------------------------------------------------------------------------
extern "C" void kernel_launch(void* const* d_in, const int* in_sizes, int n_in,
                              void* d_out, int out_size, void* d_ws, size_t ws_size,
                              hipStream_t stream)
{
  const float* x    = (const float*)d_in[0];
  const float* w1c  = (const float*)d_in[1];
  const float* b1c  = (const float*)d_in[2];
  const float* w1q  = (const float*)d_in[3];
  const float* w1k  = (const float*)d_in[4];
  const float* w1v  = (const float*)d_in[5];
  const float* w1o  = (const float*)d_in[6];
  const float* b1o  = (const float*)d_in[7];
  const float* w2c  = (const float*)d_in[8];
  const float* b2c  = (const float*)d_in[9];
  const float* w2q  = (const float*)d_in[10];
  const float* w2k  = (const float*)d_in[11];
  const float* w2v  = (const float*)d_in[12];
  const float* w2o  = (const float*)d_in[13];
  const float* b2o  = (const float*)d_in[14];
  const float* fc1w = (const float*)d_in[15];
  const float* fc1b = (const float*)d_in[16];
  const float* fc2w = (const float*)d_in[17];
  const float* fc2b = (const float*)d_in[18];
  float* out = (float*)d_out;
  float* ws = (float*)d_ws;

  float* q1   = ws + OQ1;
  float* k1   = ws + OK1;
  float* v1   = ws + OV1;
  float* loc1 = ws + OL1;
  float* agg1 = ws + OA1;
  float* t2   = ws + OT2;
  float* q2   = ws + OQ2;
  float* k2   = ws + OK2;
  float* v2   = ws + OV2;
  float* loc2 = ws + OL2;
  float* agg2 = ws + OA2;
  __bf16* h   = (__bf16*)(ws + OH);
  float* prt  = ws + OPART;
  float* hfc  = ws + OHFC;

  k1_qkv1<<<16384, 256, 0, stream>>>(x, w1q, w1k, w1v, w1c, b1c, q1, k1, v1, loc1);
  attn_kernel<16, 4, 4><<<256, 256, 0, stream>>>(q1, k1, v1, agg1);
  k3_out1<<<16384, 256, 0, stream>>>(loc1, agg1, w1o, b1o, t2);
  k4_qkv2<<<32768, 256, 0, stream>>>(t2, w2q, w2k, w2v, w2c, b2c, q2, k2, v2, loc2);
  attn_kernel<32, 8, 4><<<256, 256, 0, stream>>>(q2, k2, v2, agg2);
  k6_out2<<<32768, 256, 0, stream>>>(loc2, agg2, w2o, b2o, h);
  k7_fc1_gemm<<<256, 256, 0, stream>>>(h, fc1w, prt);
  k7c_reduce<<<1024, 256, 0, stream>>>(prt, hfc);
  k8_fc2<<<256, 256, 0, stream>>>(hfc, fc1b, fc2w, fc2b, out);
}

// Round 4
// 547.398 us; speedup vs baseline: 2.1691x; 1.2641x over previous
//
#include <hip/hip_runtime.h>
#include <math.h>

// ---------------------------------------------------------------------------
// B=256 images, N=256 tokens/image. L1: Cu=12,d=16(dh=4),r=16 -> 64ch.
// L2: Cu=64,d=32(dh=8),r=32 -> 128ch. shuffle(L1) o unshuffle(L2) == identity.
// R4: 6 kernels. k7 = no-A-LDS MFMA GEMM (conflict-free B staging, 4 blk/CU).
// k3 fused into attn1 (fp32, W in LDS). k6 fused into attn2 (bf16 MFMA epi).
// k8 fused into reduce. Selection-critical path (q/k/t2) stays exact fp32.
// ---------------------------------------------------------------------------

typedef float floatx4 __attribute__((ext_vector_type(4)));
typedef __bf16 bf16x8 __attribute__((ext_vector_type(8)));

// ---- workspace layout (float offsets), peak 50.3 MB ----
static constexpr size_t OQ1 = 0;          // [B,256,16] 1048576
static constexpr size_t OK1 = 1048576;
static constexpr size_t OV1 = 2097152;
static constexpr size_t OL1 = 3145728;    // ..4194304
static constexpr size_t OT2 = 4194304;    // [B,256,64] fp32 ..8388608
static constexpr size_t OQ2 = 0;          // [B,256,32] ..2097152 (q1/k1 dead)
static constexpr size_t OK2 = 2097152;    // ..4194304 (v1/loc1 dead)
static constexpr size_t OV2 = 8388608;    // ..10485760
static constexpr size_t OL2 = 10485760;   // ..12582912
static constexpr size_t OH  = 4194304;    // h bf16 [256,32768] = 4194304 floats (t2 dead)
static constexpr size_t OPART = 8388608;  // [16][256][1024] fp32 ..12582912 (v2/loc2 dead)

__device__ inline bf16x8 pack8(const float* f) {
  bf16x8 v;
#pragma unroll
  for (int i = 0; i < 8; ++i) v[i] = (__bf16)f[i];
  return v;
}

// ---------------- K1: pixel_unshuffle + q/k/v/local projections, layer 1 ----
__global__ __launch_bounds__(256) void k1_qkv1(
    const float* __restrict__ x, const float* __restrict__ w1q,
    const float* __restrict__ w1k, const float* __restrict__ w1v,
    const float* __restrict__ w1c, const float* __restrict__ b1c,
    float* __restrict__ q1, float* __restrict__ k1,
    float* __restrict__ v1, float* __restrict__ loc1)
{
  const int tid = threadIdx.x;
  const int slot = tid >> 6;
  const int lane = tid & 63;
  const int tok = blockIdx.x * 4 + slot;   // b*256+n
  const int b = tok >> 8, n = tok & 255;
  const int i = n >> 4, j = n & 15;
  __shared__ float ts[4][12];
  if (lane < 12) {
    const int c0 = lane >> 2, si = (lane >> 1) & 1, sj = lane & 1;
    ts[slot][lane] = x[((size_t)(b * 3 + c0) * 32 + 2 * i + si) * 32 + 2 * j + sj];
  }
  __syncthreads();
  const int mat = lane >> 4, col = lane & 15;
  const float* W = (mat == 0) ? w1q : (mat == 1) ? w1k : (mat == 2) ? w1v : w1c;
  float acc = 0.f;
#pragma unroll
  for (int c = 0; c < 12; ++c) acc += ts[slot][c] * W[c * 16 + col];
  const size_t o = (size_t)tok * 16 + col;
  if (mat == 0) q1[o] = acc;
  else if (mat == 1) k1[o] = acc;
  else if (mat == 2) v1[o] = acc;
  else loc1[o] = fmaxf(acc + b1c[col], 0.f);
}

// ---------------- attn1 + out-proj1 fused: 1 block/image -------------------
// Phase A (R3-verified): per-thread top-9 scan over LDS K, softmax, aggregate.
// Phase B: t2 = [loc1|agg] @ W1o + b1o in exact fp32, W1o in LDS,
//          4-token register blocking per thread.
__global__ __launch_bounds__(256) void attn1_out(
    const float* __restrict__ q, const float* __restrict__ k,
    const float* __restrict__ v, const float* __restrict__ loc1,
    const float* __restrict__ w1o, const float* __restrict__ b1o,
    float* __restrict__ t2)
{
  constexpr int D = 16, DH = 4, NH = 4;
  const int b = blockIdx.x;
  const int t = threadIdx.x;
  __shared__ float ks[256 * D];      // 16 KB
  __shared__ float catS[256 * 36];   // 36.9 KB  [loc(16)|agg(16)|pad(4)]
  __shared__ float wS[32 * 64];      // 8 KB
  const size_t base = (size_t)b * (256 * D);
  for (int idx = t * 4; idx < 256 * D; idx += 1024)
    *(float4*)&ks[idx] = *(const float4*)&k[base + idx];
  for (int idx = t * 4; idx < 2048; idx += 1024)
    *(float4*)&wS[idx] = *(const float4*)&w1o[idx];
  float qr[D];
  {
    const float4* qrow = (const float4*)&q[base + (size_t)t * D];
#pragma unroll
    for (int c4 = 0; c4 < D / 4; ++c4) {
      const float4 qv = qrow[c4];
      qr[4 * c4 + 0] = qv.x; qr[4 * c4 + 1] = qv.y;
      qr[4 * c4 + 2] = qv.z; qr[4 * c4 + 3] = qv.w;
    }
  }
  __syncthreads();

  float topv[9];
  int topi[9];
#pragma unroll
  for (int r = 0; r < 9; ++r) { topv[r] = -__builtin_inff(); topi[r] = 0; }

#pragma unroll 2
  for (int m = 0; m < 256; ++m) {
    const float4* kr = (const float4*)&ks[m * D];
    float p0 = 0.f, p1 = 0.f, p2 = 0.f, p3 = 0.f;
    {
      float4 kv;
      kv = kr[0];
      p0 += qr[0] * kv.x + qr[1] * kv.y + qr[2] * kv.z + qr[3] * kv.w;
      kv = kr[1];
      p1 += qr[4] * kv.x + qr[5] * kv.y + qr[6] * kv.z + qr[7] * kv.w;
      kv = kr[2];
      p2 += qr[8] * kv.x + qr[9] * kv.y + qr[10] * kv.z + qr[11] * kv.w;
      kv = kr[3];
      p3 += qr[12] * kv.x + qr[13] * kv.y + qr[14] * kv.z + qr[15] * kv.w;
    }
    const float s = (p0 + p1) + (p2 + p3);
    bool ci = s > topv[8];
#pragma unroll
    for (int i = 8; i >= 1; --i) {
      const bool cim1 = s > topv[i - 1];
      topv[i] = ci ? (cim1 ? topv[i - 1] : s) : topv[i];
      topi[i] = ci ? (cim1 ? topi[i - 1] : m) : topi[i];
      ci = cim1;
    }
    topv[0] = ci ? s : topv[0];
    topi[0] = ci ? m : topi[0];
  }

  // phase 2: per-head logits from global K rows
  float lg[NH * 9];
#pragma unroll
  for (int kk = 0; kk < 9; ++kk) {
    const float4* kr = (const float4*)&k[base + (size_t)topi[kk] * D];
    float kv[D];
#pragma unroll
    for (int c4 = 0; c4 < D / 4; ++c4) {
      const float4 x4 = kr[c4];
      kv[4 * c4 + 0] = x4.x; kv[4 * c4 + 1] = x4.y;
      kv[4 * c4 + 2] = x4.z; kv[4 * c4 + 3] = x4.w;
    }
#pragma unroll
    for (int hh = 0; hh < NH; ++hh) {
      float s = 0.f;
#pragma unroll
      for (int c = 0; c < DH; ++c) s += qr[hh * DH + c] * kv[hh * DH + c];
      lg[hh * 9 + kk] = s * 0.5f;   // 1/sqrt(4)
    }
  }
#pragma unroll
  for (int hh = 0; hh < NH; ++hh) {
    float mx = lg[hh * 9];
#pragma unroll
    for (int kk = 1; kk < 9; ++kk) mx = fmaxf(mx, lg[hh * 9 + kk]);
    float sum = 0.f;
#pragma unroll
    for (int kk = 0; kk < 9; ++kk) {
      const float e = __expf(lg[hh * 9 + kk] - mx);
      lg[hh * 9 + kk] = e; sum += e;
    }
    const float inv = 1.f / sum;
#pragma unroll
    for (int kk = 0; kk < 9; ++kk) lg[hh * 9 + kk] *= inv;
  }
  float outr[D];
#pragma unroll
  for (int c = 0; c < D; ++c) outr[c] = 0.f;
#pragma unroll
  for (int kk = 0; kk < 9; ++kk) {
    const float4* vr = (const float4*)&v[base + (size_t)topi[kk] * D];
    float vv[D];
#pragma unroll
    for (int c4 = 0; c4 < D / 4; ++c4) {
      const float4 x4 = vr[c4];
      vv[4 * c4 + 0] = x4.x; vv[4 * c4 + 1] = x4.y;
      vv[4 * c4 + 2] = x4.z; vv[4 * c4 + 3] = x4.w;
    }
#pragma unroll
    for (int hh = 0; hh < NH; ++hh) {
      const float w = lg[hh * 9 + kk];
#pragma unroll
      for (int c = 0; c < DH; ++c) outr[hh * DH + c] += w * vv[hh * DH + c];
    }
  }
  // phase B: stage cat rows, then fp32 out-projection (exact — feeds top-k 2)
#pragma unroll
  for (int c4 = 0; c4 < 4; ++c4) {
    *(float4*)&catS[t * 36 + c4 * 4] =
        *(const float4*)&loc1[(size_t)(b * 256 + t) * 16 + c4 * 4];
    *(float4*)&catS[t * 36 + 16 + c4 * 4] =
        make_float4(outr[4 * c4], outr[4 * c4 + 1], outr[4 * c4 + 2], outr[4 * c4 + 3]);
  }
  __syncthreads();
  const int tq = t >> 2, quarter = t & 3;
  float4 bia[4];
#pragma unroll
  for (int o4 = 0; o4 < 4; ++o4)
    bia[o4] = *(const float4*)&b1o[quarter * 16 + o4 * 4];
  float acc2[4][16];
#pragma unroll
  for (int tt = 0; tt < 4; ++tt)
#pragma unroll
    for (int o4 = 0; o4 < 4; ++o4) {
      acc2[tt][o4 * 4 + 0] = bia[o4].x; acc2[tt][o4 * 4 + 1] = bia[o4].y;
      acc2[tt][o4 * 4 + 2] = bia[o4].z; acc2[tt][o4 * 4 + 3] = bia[o4].w;
    }
#pragma unroll
  for (int c4 = 0; c4 < 8; ++c4) {
    float4 cat4[4];
#pragma unroll
    for (int tt = 0; tt < 4; ++tt)
      cat4[tt] = *(const float4*)&catS[(tt * 64 + tq) * 36 + c4 * 4];
#pragma unroll
    for (int o4 = 0; o4 < 4; ++o4) {
      float4 w4[4];
#pragma unroll
      for (int i = 0; i < 4; ++i)
        w4[i] = *(const float4*)&wS[(c4 * 4 + i) * 64 + quarter * 16 + o4 * 4];
#pragma unroll
      for (int tt = 0; tt < 4; ++tt) {
        acc2[tt][o4*4+0] += cat4[tt].x*w4[0].x + cat4[tt].y*w4[1].x + cat4[tt].z*w4[2].x + cat4[tt].w*w4[3].x;
        acc2[tt][o4*4+1] += cat4[tt].x*w4[0].y + cat4[tt].y*w4[1].y + cat4[tt].z*w4[2].y + cat4[tt].w*w4[3].y;
        acc2[tt][o4*4+2] += cat4[tt].x*w4[0].z + cat4[tt].y*w4[1].z + cat4[tt].z*w4[2].z + cat4[tt].w*w4[3].z;
        acc2[tt][o4*4+3] += cat4[tt].x*w4[0].w + cat4[tt].y*w4[1].w + cat4[tt].z*w4[2].w + cat4[tt].w*w4[3].w;
      }
    }
  }
#pragma unroll
  for (int tt = 0; tt < 4; ++tt) {
    float* dst = t2 + (size_t)(b * 256 + tt * 64 + tq) * 64 + quarter * 16;
#pragma unroll
    for (int o4 = 0; o4 < 4; ++o4)
      *(float4*)&dst[o4 * 4] = make_float4(acc2[tt][o4*4], acc2[tt][o4*4+1],
                                           acc2[tt][o4*4+2], acc2[tt][o4*4+3]);
  }
}

// ---------------- K4: layer-2 q/k/v/local projections (exact fp32) ---------
// 1 block/image. W (all four mats) + t2 rows staged in LDS; 4-token blocking.
__global__ __launch_bounds__(256) void k4_qkv2(
    const float* __restrict__ t2, const float* __restrict__ w2q,
    const float* __restrict__ w2k, const float* __restrict__ w2v,
    const float* __restrict__ w2c, const float* __restrict__ b2c,
    float* __restrict__ q2, float* __restrict__ k2,
    float* __restrict__ v2, float* __restrict__ loc2)
{
  const int b = blockIdx.x;
  const int tid = threadIdx.x;
  __shared__ float t2S[256 * 68];   // 69.6 KB
  __shared__ float wS[64 * 144];    // 36.9 KB  [c][mat*36 + col]
  __shared__ float bS[32];
  for (int idx = tid * 4; idx < 16384; idx += 1024) {
    const float4 vv = *(const float4*)&t2[(size_t)b * 16384 + idx];
    *(float4*)&t2S[(idx >> 6) * 68 + (idx & 63)] = vv;
  }
  for (int idx = tid * 4; idx < 2048; idx += 1024) {
    const int c = idx >> 5, col = idx & 31;
    *(float4*)&wS[c * 144 + 0 * 36 + col] = *(const float4*)&w2q[idx];
    *(float4*)&wS[c * 144 + 1 * 36 + col] = *(const float4*)&w2k[idx];
    *(float4*)&wS[c * 144 + 2 * 36 + col] = *(const float4*)&w2v[idx];
    *(float4*)&wS[c * 144 + 3 * 36 + col] = *(const float4*)&w2c[idx];
  }
  if (tid < 32) bS[tid] = b2c[tid];
  __syncthreads();
  const int tq = tid >> 2, quarter = tid & 3;   // quarter == which matrix
  float* dst = (quarter == 0) ? q2 : (quarter == 1) ? k2 : (quarter == 2) ? v2 : loc2;
#pragma unroll
  for (int ohalf = 0; ohalf < 2; ++ohalf) {
    float acc[4][16];
#pragma unroll
    for (int tt = 0; tt < 4; ++tt)
#pragma unroll
      for (int e = 0; e < 16; ++e) acc[tt][e] = 0.f;
#pragma unroll 4
    for (int c4 = 0; c4 < 16; ++c4) {
      float4 cat4[4];
#pragma unroll
      for (int tt = 0; tt < 4; ++tt)
        cat4[tt] = *(const float4*)&t2S[(tt * 64 + tq) * 68 + c4 * 4];
#pragma unroll
      for (int o4 = 0; o4 < 4; ++o4) {
        float4 w4[4];
#pragma unroll
        for (int i = 0; i < 4; ++i)
          w4[i] = *(const float4*)&wS[(c4 * 4 + i) * 144 + quarter * 36 + ohalf * 16 + o4 * 4];
#pragma unroll
        for (int tt = 0; tt < 4; ++tt) {
          acc[tt][o4*4+0] += cat4[tt].x*w4[0].x + cat4[tt].y*w4[1].x + cat4[tt].z*w4[2].x + cat4[tt].w*w4[3].x;
          acc[tt][o4*4+1] += cat4[tt].x*w4[0].y + cat4[tt].y*w4[1].y + cat4[tt].z*w4[2].y + cat4[tt].w*w4[3].y;
          acc[tt][o4*4+2] += cat4[tt].x*w4[0].z + cat4[tt].y*w4[1].z + cat4[tt].z*w4[2].z + cat4[tt].w*w4[3].z;
          acc[tt][o4*4+3] += cat4[tt].x*w4[0].w + cat4[tt].y*w4[1].w + cat4[tt].z*w4[2].w + cat4[tt].w*w4[3].w;
        }
      }
    }
#pragma unroll
    for (int tt = 0; tt < 4; ++tt) {
#pragma unroll
      for (int e = 0; e < 16; ++e) {
        float vv = acc[tt][e];
        if (quarter == 3) vv = fmaxf(vv + bS[ohalf * 16 + e], 0.f);
        acc[tt][e] = vv;
      }
      float* drow = dst + (size_t)(b * 256 + tt * 64 + tq) * 32 + ohalf * 16;
#pragma unroll
      for (int o4 = 0; o4 < 4; ++o4)
        *(float4*)&drow[o4 * 4] = make_float4(acc[tt][o4*4], acc[tt][o4*4+1],
                                              acc[tt][o4*4+2], acc[tt][o4*4+3]);
    }
  }
}

// ---------------- attn2 + out-proj2 + pixel-shuffle fused ------------------
// Phase A: fp32 scan/top-9/softmax/aggregate (selection exact).
// Phase B: h = [loc2|agg2] @ W2o + b2o via bf16 MFMA (feeds bf16 h anyway),
//          scattered bf16 stores apply the pixel-shuffle permutation.
__global__ __launch_bounds__(256) void attn2_out(
    const float* __restrict__ q, const float* __restrict__ k,
    const float* __restrict__ v, const float* __restrict__ loc2,
    const float* __restrict__ w2o, const float* __restrict__ b2o,
    __bf16* __restrict__ h)
{
  constexpr int D = 32, DH = 8, NH = 4;
  const int b = blockIdx.x;
  const int t = threadIdx.x;
  __shared__ float ks[256 * D];          // 32 KB
  __shared__ __bf16 catB[256 * 72];      // 36.9 KB  [cat(64)|pad(8)]
  __shared__ __bf16 wB[128 * 72];        // 18.4 KB  [n][k(64)|pad]
  const size_t base = (size_t)b * (256 * D);
  for (int idx = t * 4; idx < 256 * D; idx += 1024)
    *(float4*)&ks[idx] = *(const float4*)&k[base + idx];
  {  // stage W2o transposed to bf16 [n][k]
    const int n = t >> 1, khalf = t & 1;
    float wv[32];
#pragma unroll
    for (int j = 0; j < 32; ++j) wv[j] = w2o[(size_t)(khalf * 32 + j) * 128 + n];
#pragma unroll
    for (int j8 = 0; j8 < 4; ++j8)
      *(bf16x8*)&wB[n * 72 + khalf * 32 + j8 * 8] = pack8(&wv[j8 * 8]);
  }
  float qr[D];
  {
    const float4* qrow = (const float4*)&q[base + (size_t)t * D];
#pragma unroll
    for (int c4 = 0; c4 < D / 4; ++c4) {
      const float4 qv = qrow[c4];
      qr[4 * c4 + 0] = qv.x; qr[4 * c4 + 1] = qv.y;
      qr[4 * c4 + 2] = qv.z; qr[4 * c4 + 3] = qv.w;
    }
  }
  __syncthreads();

  float topv[9];
  int topi[9];
#pragma unroll
  for (int r = 0; r < 9; ++r) { topv[r] = -__builtin_inff(); topi[r] = 0; }

#pragma unroll 2
  for (int m = 0; m < 256; ++m) {
    const float4* kr = (const float4*)&ks[m * D];
    float p0 = 0.f, p1 = 0.f, p2 = 0.f, p3 = 0.f;
#pragma unroll
    for (int c4 = 0; c4 < 8; c4 += 4) {
      float4 kv;
      kv = kr[c4 + 0];
      p0 += qr[4*c4+0]*kv.x + qr[4*c4+1]*kv.y + qr[4*c4+2]*kv.z + qr[4*c4+3]*kv.w;
      kv = kr[c4 + 1];
      p1 += qr[4*c4+4]*kv.x + qr[4*c4+5]*kv.y + qr[4*c4+6]*kv.z + qr[4*c4+7]*kv.w;
      kv = kr[c4 + 2];
      p2 += qr[4*c4+8]*kv.x + qr[4*c4+9]*kv.y + qr[4*c4+10]*kv.z + qr[4*c4+11]*kv.w;
      kv = kr[c4 + 3];
      p3 += qr[4*c4+12]*kv.x + qr[4*c4+13]*kv.y + qr[4*c4+14]*kv.z + qr[4*c4+15]*kv.w;
    }
    const float s = (p0 + p1) + (p2 + p3);
    bool ci = s > topv[8];
#pragma unroll
    for (int i = 8; i >= 1; --i) {
      const bool cim1 = s > topv[i - 1];
      topv[i] = ci ? (cim1 ? topv[i - 1] : s) : topv[i];
      topi[i] = ci ? (cim1 ? topi[i - 1] : m) : topi[i];
      ci = cim1;
    }
    topv[0] = ci ? s : topv[0];
    topi[0] = ci ? m : topi[0];
  }

  float lg[NH * 9];
#pragma unroll
  for (int kk = 0; kk < 9; ++kk) {
    const float4* kr = (const float4*)&k[base + (size_t)topi[kk] * D];
    float kv[D];
#pragma unroll
    for (int c4 = 0; c4 < D / 4; ++c4) {
      const float4 x4 = kr[c4];
      kv[4 * c4 + 0] = x4.x; kv[4 * c4 + 1] = x4.y;
      kv[4 * c4 + 2] = x4.z; kv[4 * c4 + 3] = x4.w;
    }
#pragma unroll
    for (int hh = 0; hh < NH; ++hh) {
      float s = 0.f;
#pragma unroll
      for (int c = 0; c < DH; ++c) s += qr[hh * DH + c] * kv[hh * DH + c];
      lg[hh * 9 + kk] = s * 0.35355339059327373f;  // 1/sqrt(8)
    }
  }
#pragma unroll
  for (int hh = 0; hh < NH; ++hh) {
    float mx = lg[hh * 9];
#pragma unroll
    for (int kk = 1; kk < 9; ++kk) mx = fmaxf(mx, lg[hh * 9 + kk]);
    float sum = 0.f;
#pragma unroll
    for (int kk = 0; kk < 9; ++kk) {
      const float e = __expf(lg[hh * 9 + kk] - mx);
      lg[hh * 9 + kk] = e; sum += e;
    }
    const float inv = 1.f / sum;
#pragma unroll
    for (int kk = 0; kk < 9; ++kk) lg[hh * 9 + kk] *= inv;
  }
  float outr[D];
#pragma unroll
  for (int c = 0; c < D; ++c) outr[c] = 0.f;
#pragma unroll
  for (int kk = 0; kk < 9; ++kk) {
    const float4* vr = (const float4*)&v[base + (size_t)topi[kk] * D];
    float vv[D];
#pragma unroll
    for (int c4 = 0; c4 < D / 4; ++c4) {
      const float4 x4 = vr[c4];
      vv[4 * c4 + 0] = x4.x; vv[4 * c4 + 1] = x4.y;
      vv[4 * c4 + 2] = x4.z; vv[4 * c4 + 3] = x4.w;
    }
#pragma unroll
    for (int hh = 0; hh < NH; ++hh) {
      const float w = lg[hh * 9 + kk];
#pragma unroll
      for (int c = 0; c < DH; ++c) outr[hh * DH + c] += w * vv[hh * DH + c];
    }
  }
  // phase B: write cat row (loc2|agg) as bf16, then MFMA out-projection
  {
    float lv[32];
#pragma unroll
    for (int c4 = 0; c4 < 8; ++c4) {
      const float4 x4 = *(const float4*)&loc2[(size_t)(b * 256 + t) * 32 + c4 * 4];
      lv[4*c4+0] = x4.x; lv[4*c4+1] = x4.y; lv[4*c4+2] = x4.z; lv[4*c4+3] = x4.w;
    }
#pragma unroll
    for (int c8 = 0; c8 < 4; ++c8)
      *(bf16x8*)&catB[t * 72 + c8 * 8] = pack8(&lv[c8 * 8]);
#pragma unroll
    for (int c8 = 0; c8 < 4; ++c8)
      *(bf16x8*)&catB[t * 72 + 32 + c8 * 8] = pack8(&outr[c8 * 8]);
  }
  __syncthreads();
  const int w = t >> 6, lane = t & 63, qd = lane >> 4, mcol = lane & 15;
  // bias: b2o[ch] added to column ch
#pragma unroll
  for (int nc = 0; nc < 2; ++nc) {
    floatx4 acc[4][4];
#pragma unroll
    for (int mi = 0; mi < 4; ++mi)
#pragma unroll
      for (int nj = 0; nj < 4; ++nj) acc[mi][nj] = (floatx4)0.f;
    bf16x8 af[4][2], bf[4][2];
#pragma unroll
    for (int s = 0; s < 2; ++s) {
#pragma unroll
      for (int mi = 0; mi < 4; ++mi)
        af[mi][s] = *(const bf16x8*)&catB[(w * 64 + mi * 16 + mcol) * 72 + s * 32 + qd * 8];
#pragma unroll
      for (int nj = 0; nj < 4; ++nj)
        bf[nj][s] = *(const bf16x8*)&wB[((nc * 4 + nj) * 16 + mcol) * 72 + s * 32 + qd * 8];
    }
#pragma unroll
    for (int s = 0; s < 2; ++s)
#pragma unroll
      for (int mi = 0; mi < 4; ++mi)
#pragma unroll
        for (int nj = 0; nj < 4; ++nj)
          acc[mi][nj] = __builtin_amdgcn_mfma_f32_16x16x32_bf16(af[mi][s], bf[nj][s], acc[mi][nj], 0, 0, 0);
#pragma unroll
    for (int mi = 0; mi < 4; ++mi)
#pragma unroll
      for (int nj = 0; nj < 4; ++nj) {
        const int ch = (nc * 4 + nj) * 16 + mcol;
        const float bb = b2o[ch];
        const int cc = ch >> 2, si = (ch >> 1) & 1, sj = ch & 1;
#pragma unroll
        for (int r = 0; r < 4; ++r) {
          const int tok = w * 64 + mi * 16 + qd * 4 + r;
          const int i = tok >> 4, j = tok & 15;
          h[(size_t)b * 32768 + cc * 1024 + (2 * i + si) * 32 + (2 * j + sj)] =
              (__bf16)(acc[mi][nj][r] + bb);
        }
      }
  }
}

// ---------------- K7: fc1 GEMM bf16 MFMA, A-frags direct from global -------
// grid 1024: bn (32 tiles of 32 cols) x bm (2 halves of M) x bk (splitK 16).
// LDS = Bs only (4.6 KB) -> 4 blocks/CU. B staged transposed+packed,
// conflict-free (stride 36 words => bank starts n*4 mod 32).
__global__ __launch_bounds__(256) void k7_fc1_gemm(
    const __bf16* __restrict__ A,  // h bf16 [256, 32768]
    const float* __restrict__ Bw,  // fc1_w fp32 [32768, 1024]
    float* __restrict__ part)      // [16][256][1024]
{
  __shared__ __bf16 Bs[32 * 72];
  const int bn = blockIdx.x & 31;
  const int bm = (blockIdx.x >> 5) & 1;
  const int bk = blockIdx.x >> 6;
  const int n0 = bn * 32, m0 = bm * 128, k0 = bk * 2048;
  const int tid = threadIdx.x;
  const int n = tid & 31, koct = tid >> 5;          // staging role
  const int w = tid >> 6, lane = tid & 63;
  const int qd = lane >> 4, mcol = lane & 15;
  floatx4 acc[2][2];
#pragma unroll
  for (int mi = 0; mi < 2; ++mi)
#pragma unroll
    for (int ni = 0; ni < 2; ++ni) acc[mi][ni] = (floatx4)0.f;

  for (int it = 0; it < 32; ++it) {
    const int kk0 = k0 + it * 64;
    float bvals[8];
    const float* brow = Bw + (size_t)(kk0 + koct * 8) * 1024 + n0 + n;
#pragma unroll
    for (int j = 0; j < 8; ++j) bvals[j] = brow[(size_t)j * 1024];
    // A fragments straight from global (bf16, 16B contiguous per lane)
    bf16x8 af[2][2];
#pragma unroll
    for (int mi = 0; mi < 2; ++mi)
#pragma unroll
      for (int s = 0; s < 2; ++s)
        af[mi][s] = *(const bf16x8*)(A + (size_t)(m0 + w * 32 + mi * 16 + mcol) * 32768
                                       + kk0 + s * 32 + qd * 8);
    __syncthreads();  // previous iteration's Bs reads done
    *(bf16x8*)&Bs[n * 72 + koct * 8] = pack8(bvals);
    __syncthreads();
    bf16x8 bf[2][2];
#pragma unroll
    for (int ni = 0; ni < 2; ++ni)
#pragma unroll
      for (int s = 0; s < 2; ++s)
        bf[ni][s] = *(const bf16x8*)&Bs[(ni * 16 + mcol) * 72 + s * 32 + qd * 8];
#pragma unroll
    for (int s = 0; s < 2; ++s)
#pragma unroll
      for (int mi = 0; mi < 2; ++mi)
#pragma unroll
        for (int ni = 0; ni < 2; ++ni)
          acc[mi][ni] = __builtin_amdgcn_mfma_f32_16x16x32_bf16(af[mi][s], bf[ni][s], acc[mi][ni], 0, 0, 0);
  }
  float* P = part + (size_t)bk * 262144;
#pragma unroll
  for (int mi = 0; mi < 2; ++mi)
#pragma unroll
    for (int ni = 0; ni < 2; ++ni) {
      const int col = n0 + ni * 16 + mcol;
#pragma unroll
      for (int r = 0; r < 4; ++r) {
        const int row = m0 + w * 32 + mi * 16 + qd * 4 + r;
        P[(size_t)row * 1024 + col] = acc[mi][ni][r];
      }
    }
}

// ---------------- K7c+K8: splitK reduce + bias/relu + fc2 ------------------
__global__ __launch_bounds__(256) void k7c8_fc2(
    const float* __restrict__ part, const float* __restrict__ fc1b,
    const float* __restrict__ w2, const float* __restrict__ b2,
    float* __restrict__ out)
{
  const int b = blockIdx.x, t = threadIdx.x;
  const int col4 = t * 4;
  float4 s = make_float4(0.f, 0.f, 0.f, 0.f);
#pragma unroll
  for (int p = 0; p < 16; ++p) {
    const float4 x4 = *(const float4*)&part[(size_t)p * 262144 + (size_t)b * 1024 + col4];
    s.x += x4.x; s.y += x4.y; s.z += x4.z; s.w += x4.w;
  }
  const float4 bb = *(const float4*)&fc1b[col4];
  float a[4] = {fmaxf(s.x + bb.x, 0.f), fmaxf(s.y + bb.y, 0.f),
                fmaxf(s.z + bb.z, 0.f), fmaxf(s.w + bb.w, 0.f)};
  float acc[10];
#pragma unroll
  for (int o = 0; o < 10; ++o) acc[o] = 0.f;
#pragma unroll
  for (int i = 0; i < 4; ++i) {
    const float* wr = w2 + (size_t)(col4 + i) * 10;
#pragma unroll
    for (int o = 0; o < 10; ++o) acc[o] += a[i] * wr[o];
  }
  __shared__ float red[256][10];
#pragma unroll
  for (int o = 0; o < 10; ++o) red[t][o] = acc[o];
  __syncthreads();
  for (int st = 128; st > 0; st >>= 1) {
    if (t < st) {
#pragma unroll
      for (int o = 0; o < 10; ++o) red[t][o] += red[t + st][o];
    }
    __syncthreads();
  }
  if (t < 10) out[b * 10 + t] = red[0][t] + b2[t];
}

// ---------------------------------------------------------------------------
extern "C" void kernel_launch(void* const* d_in, const int* in_sizes, int n_in,
                              void* d_out, int out_size, void* d_ws, size_t ws_size,
                              hipStream_t stream)
{
  const float* x    = (const float*)d_in[0];
  const float* w1c  = (const float*)d_in[1];
  const float* b1c  = (const float*)d_in[2];
  const float* w1q  = (const float*)d_in[3];
  const float* w1k  = (const float*)d_in[4];
  const float* w1v  = (const float*)d_in[5];
  const float* w1o  = (const float*)d_in[6];
  const float* b1o  = (const float*)d_in[7];
  const float* w2c  = (const float*)d_in[8];
  const float* b2c  = (const float*)d_in[9];
  const float* w2q  = (const float*)d_in[10];
  const float* w2k  = (const float*)d_in[11];
  const float* w2v  = (const float*)d_in[12];
  const float* w2o  = (const float*)d_in[13];
  const float* b2o  = (const float*)d_in[14];
  const float* fc1w = (const float*)d_in[15];
  const float* fc1b = (const float*)d_in[16];
  const float* fc2w = (const float*)d_in[17];
  const float* fc2b = (const float*)d_in[18];
  float* out = (float*)d_out;
  float* ws = (float*)d_ws;

  float* q1   = ws + OQ1;
  float* k1   = ws + OK1;
  float* v1   = ws + OV1;
  float* loc1 = ws + OL1;
  float* t2   = ws + OT2;
  float* q2   = ws + OQ2;
  float* k2   = ws + OK2;
  float* v2   = ws + OV2;
  float* loc2 = ws + OL2;
  __bf16* h   = (__bf16*)(ws + OH);
  float* prt  = ws + OPART;

  k1_qkv1<<<16384, 256, 0, stream>>>(x, w1q, w1k, w1v, w1c, b1c, q1, k1, v1, loc1);
  attn1_out<<<256, 256, 0, stream>>>(q1, k1, v1, loc1, w1o, b1o, t2);
  k4_qkv2<<<256, 256, 0, stream>>>(t2, w2q, w2k, w2v, w2c, b2c, q2, k2, v2, loc2);
  attn2_out<<<256, 256, 0, stream>>>(q2, k2, v2, loc2, w2o, b2o, h);
  k7_fc1_gemm<<<1024, 256, 0, stream>>>(h, fc1w, prt);
  k7c8_fc2<<<256, 256, 0, stream>>>(prt, fc1b, fc2w, fc2b, out);
}